// Round 7
// baseline (95243.878 us; speedup 1.0000x reference)
//
#include <hip/hip_runtime.h>
#include <hip/hip_bf16.h>

typedef __bf16 bf16_t;
typedef __bf16 bf16x8 __attribute__((ext_vector_type(8)));
typedef float floatx4 __attribute__((ext_vector_type(4)));

#define LAYERS 8
#define BATCH  64
#define TSEQ   256
#define HDIM   512
#define GDIM   2048   // 4*H
#define UNITS  16     // LSTM units per CU slice
#define NROWS  64     // gate rows per CU slice (i,f,g,o x16)
#define WROW   1048   // weight row stride (bf16)
#define GROW   65     // gates row stride (fp32)
#define MAXM   257    // h_x slots: full sequence => virgin addresses
#define NSS    16     // h_s sibling ring depth
#define FSTR   4      // dwords per flag slot (16B)

// LDS layout (bytes)
#define W_OFF       0
#define W_BYTES     (NROWS * WROW * 2)          // 134144
#define GATES_OFF   (W_OFF + W_BYTES)
#define GATES_BYTES (BATCH * GROW * 4)          // 16640
#define BIAS_OFF    (GATES_OFF + GATES_BYTES)
#define BIAS_BYTES  (NROWS * 4)                 // 256
#define STAGE_OFF   (BIAS_OFF + BIAS_BYTES)
#define STAGE_BYTES (4 * 16 * 16 * 2)           // 2048 (per-LO-wave h staging)
#define LDS_TOTAL   (STAGE_OFF + STAGE_BYTES)   // 153088 < 160 KiB

__device__ __forceinline__ floatx4 mfma16(bf16x8 a, bf16x8 b, floatx4 c) {
    return __builtin_amdgcn_mfma_f32_16x16x32_bf16(a, b, c, 0, 0, 0);
}
__device__ __forceinline__ float sigm(float x) {
    return 1.0f / (1.0f + __expf(-x));
}
__device__ __forceinline__ unsigned pload_x(const unsigned* p) {   // L3 scope
    return __hip_atomic_load(p, __ATOMIC_RELAXED, __HIP_MEMORY_SCOPE_AGENT);
}
__device__ __forceinline__ unsigned poll_s(const unsigned* p) {    // L2, sc0
    unsigned v;
    asm volatile("global_load_dword %0, %1, off sc0\n\t"
                 "s_waitcnt vmcnt(0)"
                 : "=v"(v) : "v"(p) : "memory");
    return v;
}
__device__ __forceinline__ void drain_vm() {
    asm volatile("s_waitcnt vmcnt(0)" ::: "memory");
}
// Bounded sibling wait: fast sc0 (same-XCD L2) phase, then agent-scope (L3)
// fallback. Flags are published agent-scope write-through, so the fallback is
// guaranteed to observe them under ANY block->XCD mapping -- a mapping
// violation degrades to slower polls instead of an infinite hang (R6 risk).
__device__ __forceinline__ void wait_ge_s(const unsigned* p, unsigned tgt) {
    for (int i = 0; i < 4096; ++i)
        if ((int)(poll_s(p) - tgt) >= 0) return;
    while ((int)(pload_x(p) - tgt) < 0) __builtin_amdgcn_s_sleep(8);
}
__device__ __forceinline__ void wait_ge_x(const unsigned* p, unsigned tgt) {
    while ((int)(pload_x(p) - tgt) < 0) {}
}

// K=512 GEMM slice: all 16 A-frags loaded up front (one exposed memory
// latency instead of four -- R5's unroll-4 paid ~4 serial round trips).
__device__ __forceinline__ void gemm512(const bf16_t* ap,
                                        const bf16_t* b0, const bf16_t* b1,
                                        const bf16_t* b2, const bf16_t* b3,
                                        floatx4 acc[4]) {
    bf16x8 areg[16];
    #pragma unroll
    for (int kk = 0; kk < 16; ++kk)
        areg[kk] = *(const bf16x8*)(ap + kk * 32);
    #pragma unroll
    for (int kk = 0; kk < 16; ++kk) {
        acc[0] = mfma16(areg[kk], *(const bf16x8*)(b0 + kk * 32), acc[0]);
        acc[1] = mfma16(areg[kk], *(const bf16x8*)(b1 + kk * 32), acc[1]);
        acc[2] = mfma16(areg[kk], *(const bf16x8*)(b2 + kk * 32), acc[2]);
        acc[3] = mfma16(areg[kk], *(const bf16x8*)(b3 + kk * 32), acc[3]);
    }
}

// prep: x -> bf16 [t][b][e]; zero h_s ring + both flag arrays.
__global__ void prep(const float* __restrict__ x, bf16_t* __restrict__ x_bf,
                     bf16_t* __restrict__ h_s, unsigned* __restrict__ prog_x,
                     unsigned* __restrict__ prog_s) {
    const int gtid = blockIdx.x * blockDim.x + threadIdx.x;
    const int nthr = gridDim.x * blockDim.x;
    for (int i = gtid; i < BATCH * TSEQ * HDIM; i += nthr) {
        int e = i & (HDIM - 1);
        int b = (i >> 9) & 63;
        int t = i >> 15;
        x_bf[i] = (bf16_t)x[((size_t)b * TSEQ + t) * HDIM + e];
    }
    for (int i = gtid; i < LAYERS * NSS * BATCH * HDIM / 2; i += nthr)
        ((unsigned*)h_s)[i] = 0u;
    for (int i = gtid; i < 256 * 4 * FSTR; i += nthr) {
        prog_x[i] = 0u; prog_s[i] = 0u;
    }
}

// Wave-specialized self-timed LSTM. Per block (1/CU, layer=blk&7):
//   LO waves 0-3: lo-GEMM (x / producer h_x stream from L3; producer flag
//     pre-polled at the bottom of the previous iteration so the L3 latency
//     overlaps), then after the barrier: combine with HI's partial (LDS),
//     cell update (c-state in registers -- MFMA quadruple layout gives one
//     lane all 4 gates of a (batch,unit)), pack h via LDS stage -> dword
//     stores: h_s plain (L2) + flag, h_x agent write-through (L3) + flag.
//   HI waves 4-7: poll sibling flags, hi-GEMM from h_s (L2), partial -> LDS.
// Within-layer critical cycle: {poll + hi-GEMM + barrier + cell + L2 drain
// + flag}; the cross-XCD stream and L3 flag latency ride concurrently.
__global__ void lstm_main(const float* __restrict__ w_ih,
                          const float* __restrict__ w_hh,
                          const float* __restrict__ b_ih,
                          const float* __restrict__ b_hh,
                          const bf16_t* __restrict__ x_bf,  // [T][B][H]
                          bf16_t* __restrict__ h_x,         // [L][M][B][H]
                          bf16_t* __restrict__ h_s,         // [L][NSS][B][H]
                          float*  __restrict__ finals,      // [B][L][H]
                          unsigned* __restrict__ prog_x,    // [256*4] x FSTR
                          unsigned* __restrict__ prog_s,    // [256*4] x FSTR
                          int M, int F)
{
    extern __shared__ char smem[];
    bf16_t* wlds  = (bf16_t*)(smem + W_OFF);
    float*  gates = (float*)(smem + GATES_OFF);
    float*  bias  = (float*)(smem + BIAS_OFF);
    bf16_t* stage = (bf16_t*)(smem + STAGE_OFF);

    const int tid   = threadIdx.x;
    const int blk   = blockIdx.x;
    const int layer = blk & 7;
    const int slice = blk >> 3;
    const int u0    = slice * UNITS;
    const size_t lstride = (size_t)M * BATCH * HDIM;
    const bool ringmode = (M < MAXM);

    // ---- weights -> LDS; row r: gate = (r>>4)*512 + u0 + (r&15) ----
    for (int r = 0; r < NROWS; ++r) {
        const int gate = ((r >> 4) * 512) + u0 + (r & 15);
        const float* srcA = w_ih + ((size_t)layer * GDIM + gate) * HDIM;
        const float* srcB = w_hh + ((size_t)layer * GDIM + gate) * HDIM;
        wlds[r * WROW + tid]       = (bf16_t)srcA[tid];
        wlds[r * WROW + 512 + tid] = (bf16_t)srcB[tid];
    }
    if (tid < NROWS) {
        const int gate = ((tid >> 4) * 512) + u0 + (tid & 15);
        bias[tid] = b_ih[layer * GDIM + gate] + b_hh[layer * GDIM + gate];
    }
    __syncthreads();

    const int lane = tid & 63;
    const int wave = tid >> 6;
    const bool isLO = (wave < 4);
    const int w    = wave & 3;           // m-tile index for both groups
    const int quad = lane >> 4;
    const int l15  = lane & 15;
    const int m0   = w * 16;
    const int arow = m0 + l15;
    const int sb   = lane & 31;          // sibling block index for polls
    const int wsel = lane >> 5;          // flag-wave selector (2 flags/lane)

    // B-fragment bases: LO uses cols 0..511 (W_ih), HI cols 512..1023 (W_hh)
    const int hoff = isLO ? 0 : 512;
    const bf16_t* bb0 = wlds + (size_t)(0 * 16 + l15) * WROW + hoff + quad * 8;
    const bf16_t* bb1 = wlds + (size_t)(1 * 16 + l15) * WROW + hoff + quad * 8;
    const bf16_t* bb2 = wlds + (size_t)(2 * 16 + l15) * WROW + hoff + quad * 8;
    const bf16_t* bb3 = wlds + (size_t)(3 * 16 + l15) * WROW + hoff + quad * 8;

    float bias_r[4], cstate[4] = {0.f, 0.f, 0.f, 0.f};
    #pragma unroll
    for (int n = 0; n < 4; ++n) bias_r[n] = bias[n * 16 + l15];

    // initial producer poll (t=0 needs prog_x >= 1)
    if (isLO && layer > 0) {
        const unsigned* f0 = prog_x + ((layer - 1 + 8 * sb) * 4 + wsel) * FSTR;
        wait_ge_x(f0, 1u);
        wait_ge_x(f0 + 2 * FSTR, 1u);
    }

    for (int t = 0; t < TSEQ; ++t) {
        floatx4 acc[4];
        #pragma unroll
        for (int n = 0; n < 4; ++n) acc[n] = {0.f, 0.f, 0.f, 0.f};

        if (isLO) {
            if (ringmode && (t % F) == 0)
                __builtin_amdgcn_fence(__ATOMIC_ACQUIRE, "agent");
            const bf16_t* src = (layer == 0)
                ? (x_bf + (size_t)t * BATCH * HDIM)
                : (h_x + (size_t)(layer - 1) * lstride
                       + (size_t)((t + 1) % M) * BATCH * HDIM);
            gemm512(src + (size_t)arow * HDIM + quad * 8, bb0, bb1, bb2, bb3, acc);
        } else {
            if (t > 0) {
                const unsigned* f0 =
                    prog_s + ((layer + 8 * sb) * 4 + wsel) * FSTR;
                wait_ge_s(f0, (unsigned)t);
                wait_ge_s(f0 + 2 * FSTR, (unsigned)t);
            }
            const bf16_t* src = h_s
                + ((size_t)layer * NSS + ((t + NSS - 1) & (NSS - 1)))
                  * BATCH * HDIM;
            gemm512(src + (size_t)arow * HDIM + quad * 8, bb0, bb1, bb2, bb3, acc);
            #pragma unroll
            for (int n = 0; n < 4; ++n)
                #pragma unroll
                for (int r = 0; r < 4; ++r)
                    gates[(m0 + quad * 4 + r) * GROW + n * 16 + l15] = acc[n][r];
        }
        __syncthreads();   // HI partial visible; also orders gates reuse

        if (isLO) {
            // combine + cell: lane owns batches m0+quad*4+r, unit u0+l15
            float hf[4];
            #pragma unroll
            for (int r = 0; r < 4; ++r) {
                const int gb = (m0 + quad * 4 + r) * GROW + l15;
                const float iv = acc[0][r] + gates[gb]      + bias_r[0];
                const float fv = acc[1][r] + gates[gb + 16] + bias_r[1];
                const float gv = acc[2][r] + gates[gb + 32] + bias_r[2];
                const float ov = acc[3][r] + gates[gb + 48] + bias_r[3];
                const float c  = sigm(fv) * cstate[r] + sigm(iv) * tanhf(gv);
                cstate[r] = c;
                hf[r] = sigm(ov) * tanhf(c);
            }
            // pack h to dwords via per-wave LDS stage (wave-synchronous)
            bf16_t* st = stage + w * 256;
            #pragma unroll
            for (int r = 0; r < 4; ++r)
                st[(quad * 4 + r) * 16 + l15] = (bf16_t)hf[r];
            asm volatile("s_waitcnt lgkmcnt(0)" ::: "memory");
            const int p0 = lane, p1 = lane + 64;   // 128 (b,unit-pair) items
            const uint32_t v0 = *(const uint32_t*)(st + (p0 >> 3) * 16 + (p0 & 7) * 2);
            const uint32_t v1 = *(const uint32_t*)(st + (p1 >> 3) * 16 + (p1 & 7) * 2);
            const int b0r = m0 + (p0 >> 3), c0 = u0 + (p0 & 7) * 2;
            const int b1r = m0 + (p1 >> 3), c1 = u0 + (p1 & 7) * 2;

            const size_t so = ((size_t)layer * NSS + (t & (NSS - 1)))
                              * BATCH * HDIM;
            __hip_atomic_store((uint32_t*)(h_s + so + (size_t)b0r * HDIM + c0),
                               v0, __ATOMIC_RELAXED, __HIP_MEMORY_SCOPE_WORKGROUP);
            __hip_atomic_store((uint32_t*)(h_s + so + (size_t)b1r * HDIM + c1),
                               v1, __ATOMIC_RELAXED, __HIP_MEMORY_SCOPE_WORKGROUP);
            if (t == TSEQ - 1) {
                #pragma unroll
                for (int r = 0; r < 4; ++r)
                    finals[((size_t)(m0 + quad * 4 + r) * LAYERS + layer)
                           * HDIM + u0 + l15] = hf[r];
            }
            drain_vm();        // h_s acked at L2 -> publish sibling flag
            // agent-scope publish: write-through (visible at L2 en route and
            // at L3 for the fallback poll path)
            if (lane == 0)
                __hip_atomic_store(prog_s + ((size_t)blk * 4 + w) * FSTR,
                                   (unsigned)(t + 1), __ATOMIC_RELAXED,
                                   __HIP_MEMORY_SCOPE_AGENT);

            if (layer < 7) {
                if (ringmode && t >= M - 1) {     // h_x slot-reuse guard
                    const unsigned* f0 =
                        prog_x + ((layer + 1 + 8 * sb) * 4 + wsel) * FSTR;
                    wait_ge_x(f0, (unsigned)(t + 2 - M));
                    wait_ge_x(f0 + 2 * FSTR, (unsigned)(t + 2 - M));
                }
                const size_t xo = (size_t)layer * lstride
                                + (size_t)((t + 1) % M) * BATCH * HDIM;
                __hip_atomic_store((uint32_t*)(h_x + xo + (size_t)b0r * HDIM + c0),
                                   v0, __ATOMIC_RELAXED, __HIP_MEMORY_SCOPE_AGENT);
                __hip_atomic_store((uint32_t*)(h_x + xo + (size_t)b1r * HDIM + c1),
                                   v1, __ATOMIC_RELAXED, __HIP_MEMORY_SCOPE_AGENT);
            }
            // pre-poll producer for t+1 while h_x stores are in flight
            if (layer > 0 && t + 1 < TSEQ) {
                const unsigned* f0 =
                    prog_x + ((layer - 1 + 8 * sb) * 4 + wsel) * FSTR;
                wait_ge_x(f0, (unsigned)(t + 2));
                wait_ge_x(f0 + 2 * FSTR, (unsigned)(t + 2));
            }
            if (layer < 7) {
                drain_vm();    // h_x acked at L3 -> publish cross flag
                if (lane == 0)
                    __hip_atomic_store(prog_x + ((size_t)blk * 4 + w) * FSTR,
                                       (unsigned)(t + 1), __ATOMIC_RELAXED,
                                       __HIP_MEMORY_SCOPE_AGENT);
            }
        }
    }
}

// FF head: per (b,l): 512 -> silu(128) -> 64, interleave split + softplus.
__global__ void ff_epilogue(const float* __restrict__ finals,  // [B][L][H]
                            const float* __restrict__ ff1_w,   // [128][512]
                            const float* __restrict__ ff1_b,
                            const float* __restrict__ ff2_w,   // [64][128]
                            const float* __restrict__ ff2_b,
                            float* __restrict__ out)           // mean|scale
{
    __shared__ float fin[HDIM];
    __shared__ float hid[128];
    const int blk = blockIdx.x;        // b*8 + l
    const int b = blk >> 3, l = blk & 7;
    const int tid = threadIdx.x;       // 128

    const float* frow = finals + ((size_t)b * LAYERS + l) * HDIM;
    for (int k = tid; k < HDIM; k += 128) fin[k] = frow[k];
    __syncthreads();

    float acc = ff1_b[tid];
    const float* w1 = ff1_w + (size_t)tid * HDIM;
    #pragma unroll 4
    for (int k = 0; k < HDIM; ++k) acc = fmaf(fin[k], w1[k], acc);
    hid[tid] = acc * (1.0f / (1.0f + __expf(-acc)));   // silu
    __syncthreads();

    if (tid < 64) {
        float o = ff2_b[tid];
        const float* w2 = ff2_w + (size_t)tid * 128;
        #pragma unroll 4
        for (int k = 0; k < 128; ++k) o = fmaf(hid[k], w2[k], o);
        const int j = l * 64 + tid;        // column in (B, 512) flat h
        const int col = j >> 1;
        if ((j & 1) == 0) {
            out[b * 256 + col] = o;                        // mean
        } else {
            const float sp = fmaxf(o, 0.0f) + log1pf(__expf(-fabsf(o)));
            out[64 * 256 + b * 256 + col] = sp + 1e-8f;    // scale
        }
    }
}

extern "C" void kernel_launch(void* const* d_in, const int* in_sizes, int n_in,
                              void* d_out, int out_size, void* d_ws, size_t ws_size,
                              hipStream_t stream) {
    const float* x     = (const float*)d_in[0];
    const float* w_ih  = (const float*)d_in[1];
    const float* w_hh  = (const float*)d_in[2];
    const float* b_ih  = (const float*)d_in[3];
    const float* b_hh  = (const float*)d_in[4];
    const float* ff1_w = (const float*)d_in[5];
    const float* ff1_b = (const float*)d_in[6];
    const float* ff2_w = (const float*)d_in[7];
    const float* ff2_b = (const float*)d_in[8];
    float* out = (float*)d_out;

    char* ws = (char*)d_ws;
    bf16_t* x_bf = (bf16_t*)ws;                                    // 16 MB
    size_t off = (size_t)TSEQ * BATCH * HDIM * 2;
    float* finals = (float*)(ws + off);                            // 1 MB
    off += (size_t)BATCH * LAYERS * HDIM * 4;
    unsigned* prog_x = (unsigned*)(ws + off);  off += 256 * 4 * FSTR * 4;
    unsigned* prog_s = (unsigned*)(ws + off);  off += 256 * 4 * FSTR * 4;
    off = (off + 255) & ~(size_t)255;
    bf16_t* h_s = (bf16_t*)(ws + off);                             // 8 MB
    off += (size_t)LAYERS * NSS * BATCH * HDIM * 2;
    off = (off + 255) & ~(size_t)255;

    const size_t per_slot = (size_t)LAYERS * BATCH * HDIM * 2;     // 512 KB
    int M = MAXM;
    if (ws_size > off) {
        size_t fit = (ws_size - off) / per_slot;
        if (fit < (size_t)M) M = (int)fit;
    } else {
        M = 5;
    }
    if (M < 5) M = 5;
    const int F = M - 1;
    bf16_t* h_x = (bf16_t*)(ws + off);

    (void)in_sizes; (void)n_in; (void)out_size;

    hipFuncSetAttribute((const void*)lstm_main,
                        hipFuncAttributeMaxDynamicSharedMemorySize, LDS_TOTAL);

    prep<<<dim3(1024), dim3(256), 0, stream>>>(x, x_bf, h_s, prog_x, prog_s);

    void* args[] = {(void*)&w_ih, (void*)&w_hh, (void*)&b_ih, (void*)&b_hh,
                    (void*)&x_bf, (void*)&h_x, (void*)&h_s, (void*)&finals,
                    (void*)&prog_x, (void*)&prog_s, (void*)&M, (void*)&F};
    hipLaunchCooperativeKernel((const void*)lstm_main, dim3(256), dim3(512),
                               args, LDS_TOTAL, stream);

    ff_epilogue<<<dim3(512), dim3(128), 0, stream>>>(finals, ff1_w, ff1_b,
                                                     ff2_w, ff2_b, out);
}